// Round 9
// baseline (385.443 us; speedup 1.0000x reference)
//
#include <hip/hip_runtime.h>
#include <stdint.h>

#define L_DIM 2048
#define B_DIM 32
#define ENC_DIM 1024
#define M_DIM (L_DIM * B_DIM)

typedef __attribute__((ext_vector_type(4))) float f32x4;
typedef __attribute__((ext_vector_type(4))) unsigned int uint4v;
typedef __attribute__((ext_vector_type(8))) short short8;
typedef __attribute__((ext_vector_type(4))) short short4v;
typedef __attribute__((ext_vector_type(4))) __bf16 bf16x4;

static __device__ __forceinline__ float fast_tanh(float x) {
  float cx = fminf(fmaxf(x, -15.f), 15.f);
  float e = __expf(2.f * cx);
  return (e - 1.f) * __frcp_rn(e + 1.f);
}

static __device__ __forceinline__ float bf2f(unsigned short u) {
  return __builtin_bit_cast(float, (unsigned int)u << 16);
}

static __device__ __forceinline__ void load_lds16(const void* g, void* l) {
  __builtin_amdgcn_global_load_lds((const __attribute__((address_space(1))) void*)g,
                                   (__attribute__((address_space(3))) void*)l, 16, 0, 0);
}

// ---------------- enc fp32 -> bf16 copy (64M elems) -------------------------------
__global__ __launch_bounds__(256) void k_enc_bf16(const float* __restrict__ enc,
                                                  unsigned short* __restrict__ encB) {
  const int t = blockIdx.x * 256 + threadIdx.x;   // 524288 threads
#pragma unroll
  for (int it = 0; it < 16; ++it) {
    size_t i = ((size_t)t + (size_t)it * 524288) << 3;   // 8 floats per thread-iter
    f32x4 a = *reinterpret_cast<const f32x4*>(enc + i);
    f32x4 b = *reinterpret_cast<const f32x4*>(enc + i + 4);
    bf16x4 pa = {(__bf16)a.x, (__bf16)a.y, (__bf16)a.z, (__bf16)a.w};
    bf16x4 pb = {(__bf16)b.x, (__bf16)b.y, (__bf16)b.z, (__bf16)b.w};
    union { bf16x4 v; unsigned int u[2]; } ua, ub;
    ua.v = pa; ub.v = pb;
    uint4v o;
    o.x = ua.u[0]; o.y = ua.u[1]; o.z = ub.u[0]; o.w = ub.u[1];
    *reinterpret_cast<uint4v*>(encB + i) = o;
  }
}

// ---------------- W_enc [K=1024][N=1024] fp32  ->  WT [N][K] bf16 -----------------
__global__ __launch_bounds__(256) void k_wt(const float* __restrict__ W,
                                            unsigned short* __restrict__ WT) {
  __shared__ float tile[64][65];
  const int t = threadIdx.x;
  const int k0 = (blockIdx.x & 15) << 6, n0 = (blockIdx.x >> 4) << 6;
#pragma unroll
  for (int i = 0; i < 16; ++i) {
    int idx = t + (i << 8);
    tile[idx >> 6][idx & 63] = W[(size_t)(k0 + (idx >> 6)) * 1024 + n0 + (idx & 63)];
  }
  __syncthreads();
#pragma unroll
  for (int i = 0; i < 16; ++i) {
    int idx = t + (i << 8);
    int r = idx >> 6, c = idx & 63;
    WT[(size_t)(n0 + r) * 1024 + k0 + c] =
        __builtin_bit_cast(unsigned short, (__bf16)tile[c][r]);
  }
}

// ---------------- q partial: grid 64 = 8 a-blocks x 8 h-blocks, 128 thr -----------
__global__ __launch_bounds__(128) void k_qpart(const float* __restrict__ hidden,
                                               const float* __restrict__ Wh,
                                               float* __restrict__ pq) {
  const int ablk = blockIdx.x & 7, hblk = blockIdx.x >> 3;
  const int a = (ablk << 7) + threadIdx.x;
  float acc[32];
#pragma unroll
  for (int b = 0; b < 32; ++b) acc[b] = 0.f;
  const int h0 = hblk << 7;
  for (int h = h0; h < h0 + 128; ++h) {
    float wv = Wh[(size_t)h * 1024 + a];
#pragma unroll
    for (int b = 0; b < 32; ++b) acc[b] = fmaf(hidden[(b << 10) + h], wv, acc[b]);
  }
#pragma unroll
  for (int b = 0; b < 32; ++b) pq[((size_t)hblk << 15) + (b << 10) + a] = acc[b];
}

__global__ __launch_bounds__(256) void k_qred(const float* __restrict__ pq,
                                              const float* __restrict__ ba,
                                              float* __restrict__ q) {
  int i = blockIdx.x * 256 + threadIdx.x;  // 32768
  float s = ba[i & 1023];
#pragma unroll
  for (int j = 0; j < 8; ++j) s += pq[((size_t)j << 15) + i];
  q[i] = s;
}

// ================= fused keys-GEMM + tanh.v reduction, 128^2 2-phase dbuf ========
// Proven R6 128x128/BK=64/4-wave kernel + minimum-2-phase: stage(t+1) is issued
// BEFORE compute(t), so the __syncthreads vmcnt(0) drain at tile end waits on
// loads that already had ~900+ cycles of MFMA/ds_read to land. Double-buffered
// LDS (65KB -> 2 blocks/CU; trades 1 block of occupancy for self-hiding).
// WAR-safe: buf[cur^1]'s readers retired (lgkmcnt before MFMA) before the
// previous barrier. q folded into MFMA C-in. pl[nblk8][b][l] transposed output.
__global__ __launch_bounds__(256, 2) void k_logits_db(const unsigned short* __restrict__ encB,
                                                      const unsigned short* __restrict__ WT,
                                                      const float* __restrict__ qv,
                                                      const float* __restrict__ v,
                                                      float* __restrict__ pl) {
  __shared__ __align__(16) unsigned short As[2][128 * 64];
  __shared__ __align__(16) unsigned short Bs[2][128 * 64];
  __shared__ float red[2][128];

  const int tid = threadIdx.x;
  // XCD-aware mapping: all 8 n-blocks of an m-panel land on one XCD
  const int xcd = blockIdx.x & 7, slot = blockIdx.x >> 3;
  const int nblk = slot & 7;
  const int mblk = xcd + ((slot >> 3) << 3);
  const int row0 = mblk << 7;
  const int n0 = nblk << 7;

  const int w = tid >> 6, lane = tid & 63;
  const int wr = w >> 1, wc = w & 1;
  const int g = lane >> 4, rr = lane & 15;
  const int srow = lane >> 3, sjj = lane & 7;   // staging row-offset / 16B-block

  float vreg[4];
#pragma unroll
  for (int nf = 0; nf < 4; ++nf) vreg[nf] = v[n0 + wc * 64 + nf * 16 + rr];

  // seed accumulator with q[b][col]: C/D row = wr*64+mf*16+g*4+rg, b = row&31
  f32x4 acc[4][4];
#pragma unroll
  for (int mf = 0; mf < 4; ++mf)
#pragma unroll
    for (int nf = 0; nf < 4; ++nf)
#pragma unroll
      for (int rg = 0; rg < 4; ++rg) {
        int b = ((mf & 1) << 4) + (g << 2) + rg;
        acc[mf][nf][rg] = qv[((size_t)b << 10) + n0 + wc * 64 + nf * 16 + rr];
      }

  // prologue: stage K-tile 0 into buf 0
#pragma unroll
  for (int c = 0; c < 4; ++c) {
    int r = w * 32 + c * 8 + srow;
    int blk = sjj ^ (r & 7);
    const char* bsrc = (const char*)WT + ((((size_t)(n0 + r) << 10)) << 1) + (blk << 4);
    load_lds16(bsrc, (void*)&Bs[0][(w * 32 + c * 8) * 64]);
    const char* asrc = (const char*)encB + ((((size_t)(row0 + r) << 10)) << 1) + (blk << 4);
    load_lds16(asrc, (void*)&As[0][(w * 32 + c * 8) * 64]);
  }
  __syncthreads();

#pragma unroll 2
  for (int kt = 0; kt < 16; ++kt) {
    const int cur = kt & 1;
    // 1) stage tile kt+1 into the other buffer (issued first; latency hides
    //    under this tile's compute)
    if (kt < 15) {
      const int k1 = (kt + 1) << 6;
#pragma unroll
      for (int c = 0; c < 4; ++c) {
        int r = w * 32 + c * 8 + srow;
        int blk = sjj ^ (r & 7);
        const char* bsrc =
            (const char*)WT + ((((size_t)(n0 + r) << 10) + k1) << 1) + (blk << 4);
        load_lds16(bsrc, (void*)&Bs[cur ^ 1][(w * 32 + c * 8) * 64]);
        const char* asrc =
            (const char*)encB + ((((size_t)(row0 + r) << 10) + k1) << 1) + (blk << 4);
        load_lds16(asrc, (void*)&As[cur ^ 1][(w * 32 + c * 8) * 64]);
      }
    }
    // 2) compute tile kt from buf[cur]
#pragma unroll
    for (int kk = 0; kk < 2; ++kk) {
      short8 af[4], bfr[4];
#pragma unroll
      for (int mf = 0; mf < 4; ++mf) {
        int r = wr * 64 + mf * 16 + rr;
        int blk = (kk * 4 + g) ^ (r & 7);
        af[mf] = *reinterpret_cast<const short8*>(&As[cur][r * 64 + (blk << 3)]);
      }
#pragma unroll
      for (int nf = 0; nf < 4; ++nf) {
        int r = wc * 64 + nf * 16 + rr;
        int blk = (kk * 4 + g) ^ (r & 7);
        bfr[nf] = *reinterpret_cast<const short8*>(&Bs[cur][r * 64 + (blk << 3)]);
      }
#pragma unroll
      for (int mf = 0; mf < 4; ++mf)
#pragma unroll
        for (int nf = 0; nf < 4; ++nf)
          acc[mf][nf] = __builtin_amdgcn_mfma_f32_16x16x32_bf16(af[mf], bfr[nf], acc[mf][nf], 0, 0, 0);
    }
    // 3) tile boundary: drains vmcnt (stages issued a full compute phase ago)
    __syncthreads();
  }

  // --- epilogue: tanh(S+q)*v, reduce over this block's 128 n-columns ---
#pragma unroll
  for (int mf = 0; mf < 4; ++mf) {
#pragma unroll
    for (int rg = 0; rg < 4; ++rg) {
      int lrow = wr * 64 + mf * 16 + g * 4 + rg;   // C/D: col=lane&15, row=4*(lane>>4)+reg
      float s = 0.f;
#pragma unroll
      for (int nf = 0; nf < 4; ++nf) s += fast_tanh(acc[mf][nf][rg]) * vreg[nf];
      s += __shfl_xor(s, 1);
      s += __shfl_xor(s, 2);
      s += __shfl_xor(s, 4);
      s += __shfl_xor(s, 8);
      if (rr == 0) red[wc][lrow] = s;
    }
  }
  __syncthreads();
  if (tid < 128) {
    int row = row0 + tid;                          // row = l*32 + b
    pl[((size_t)nblk << 16) + ((size_t)(row & 31) << 11) + (row >> 5)] =
        red[0][tid] + red[1][tid];
  }
}

// ---- fallback (small ws): R3 kernel — A fp32->cvt->ds_write, 128^2, pl[8] -------
__global__ __launch_bounds__(256, 3) void k_logits_cvt(const float* __restrict__ enc,
                                                       const unsigned short* __restrict__ WT,
                                                       const float* __restrict__ qv,
                                                       const float* __restrict__ v,
                                                       float* __restrict__ pl) {
  __shared__ __align__(16) unsigned short As[128 * 64];
  __shared__ __align__(16) unsigned short Bs[128 * 64];
  __shared__ float red[2][128];

  const int tid = threadIdx.x;
  const int xcd = blockIdx.x & 7, slot = blockIdx.x >> 3;
  const int nblk = slot & 7;
  const int mblk = xcd + ((slot >> 3) << 3);
  const int row0 = mblk << 7;
  const int n0 = nblk << 7;

  const int w = tid >> 6, lane = tid & 63;
  const int wr = w >> 1, wc = w & 1;
  const int g = lane >> 4, rr = lane & 15;

  float vreg[4];
#pragma unroll
  for (int nf = 0; nf < 4; ++nf) vreg[nf] = v[n0 + wc * 64 + nf * 16 + rr];

  f32x4 acc[4][4];
#pragma unroll
  for (int mf = 0; mf < 4; ++mf)
#pragma unroll
    for (int nf = 0; nf < 4; ++nf)
#pragma unroll
      for (int rg = 0; rg < 4; ++rg) {
        int b = ((mf & 1) << 4) + (g << 2) + rg;
        acc[mf][nf][rg] = qv[((size_t)b << 10) + n0 + wc * 64 + nf * 16 + rr];
      }

  const int ar = tid >> 4;
  const int ac4 = tid & 15;
  const int ablk = ((ac4 >> 1) ^ (ar & 7));
  const int brow = lane >> 3, bjj = lane & 7;

  for (int kt = 0; kt < 16; ++kt) {
    const int k0 = kt << 6;
    __syncthreads();
#pragma unroll
    for (int c = 0; c < 4; ++c) {
      int nrow = w * 32 + c * 8 + brow;
      int blk = bjj ^ (brow & 7);
      const char* src = (const char*)WT + (((size_t)(n0 + nrow) << 10) + k0) * 2 + (blk << 4);
      load_lds16(src, (void*)&Bs[(w * 32 + c * 8) * 64]);
    }
#pragma unroll
    for (int i = 0; i < 8; ++i) {
      int r = ar + (i << 4);
      f32x4 a4 = *reinterpret_cast<const f32x4*>(enc + (((size_t)(row0 + r)) << 10) + k0 + (ac4 << 2));
      bf16x4 pk = {(__bf16)a4.x, (__bf16)a4.y, (__bf16)a4.z, (__bf16)a4.w};
      *reinterpret_cast<bf16x4*>(&As[r * 64 + (ablk << 3) + ((ac4 & 1) << 2)]) = pk;
    }
    __syncthreads();
#pragma unroll
    for (int kk = 0; kk < 2; ++kk) {
      short8 af[4], bfr[4];
#pragma unroll
      for (int mf = 0; mf < 4; ++mf) {
        int r = wr * 64 + mf * 16 + rr;
        int blk = (kk * 4 + g) ^ (r & 7);
        af[mf] = *reinterpret_cast<const short8*>(&As[r * 64 + (blk << 3)]);
      }
#pragma unroll
      for (int nf = 0; nf < 4; ++nf) {
        int r = wc * 64 + nf * 16 + rr;
        int blk = (kk * 4 + g) ^ (r & 7);
        bfr[nf] = *reinterpret_cast<const short8*>(&Bs[r * 64 + (blk << 3)]);
      }
#pragma unroll
      for (int mf = 0; mf < 4; ++mf)
#pragma unroll
        for (int nf = 0; nf < 4; ++nf)
          acc[mf][nf] = __builtin_amdgcn_mfma_f32_16x16x32_bf16(af[mf], bfr[nf], acc[mf][nf], 0, 0, 0);
    }
  }

#pragma unroll
  for (int mf = 0; mf < 4; ++mf) {
#pragma unroll
    for (int rg = 0; rg < 4; ++rg) {
      int lrow = wr * 64 + mf * 16 + g * 4 + rg;
      float s = 0.f;
#pragma unroll
      for (int nf = 0; nf < 4; ++nf) s += fast_tanh(acc[mf][nf][rg]) * vreg[nf];
      s += __shfl_xor(s, 1);
      s += __shfl_xor(s, 2);
      s += __shfl_xor(s, 4);
      s += __shfl_xor(s, 8);
      if (rr == 0) red[wc][lrow] = s;
    }
  }
  __syncthreads();
  if (tid < 128) {
    int row = row0 + tid;
    pl[((size_t)nblk << 16) + ((size_t)(row & 31) << 11) + (row >> 5)] =
        red[0][tid] + red[1][tid];
  }
}

// ---------------- softmax over l, per b (NP partial planes) ----------------------
template <int NP>
__global__ __launch_bounds__(256) void k_softmax(const float* __restrict__ pl,
                                                 const float* __restrict__ mask,
                                                 float* __restrict__ al) {
  const int b = blockIdx.x, t = threadIdx.x;
  __shared__ float sr[256];
  float lg[8];
  float mx = -3.4e38f;
#pragma unroll
  for (int i = 0; i < 8; ++i) {
    int l = t + (i << 8);
    float s = mask[(l << 5) + b];
#pragma unroll
    for (int nb = 0; nb < NP; ++nb) s += pl[((size_t)nb << 16) + (b << 11) + l];
    lg[i] = s;
    mx = fmaxf(mx, s);
  }
  sr[t] = mx;
  __syncthreads();
  for (int off = 128; off > 0; off >>= 1) {
    if (t < off) sr[t] = fmaxf(sr[t], sr[t + off]);
    __syncthreads();
  }
  const float M = sr[0];
  __syncthreads();
  float sum = 0.f;
#pragma unroll
  for (int i = 0; i < 8; ++i) {
    lg[i] = __expf(lg[i] - M);
    sum += lg[i];
  }
  sr[t] = sum;
  __syncthreads();
  for (int off = 128; off > 0; off >>= 1) {
    if (t < off) sr[t] += sr[t + off];
    __syncthreads();
  }
  const float inv = 1.f / sr[0];
#pragma unroll
  for (int i = 0; i < 8; ++i) {
    int l = t + (i << 8);
    al[(l << 5) + b] = lg[i] * inv;
  }
}

// ---------------- context partials from bf16 enc: grid = 32 chunks x 32 b --------
__global__ __launch_bounds__(256) void k_ctx_bf(const unsigned short* __restrict__ encB,
                                                const float* __restrict__ al,
                                                float* __restrict__ pctx) {
  const int b = blockIdx.x & 31, ch = blockIdx.x >> 5;
  const int t = threadIdx.x;
  __shared__ float wl[64];
  if (t < 64) wl[t] = al[(((ch << 6) + t) << 5) + b];
  __syncthreads();
  f32x4 acc = (f32x4){0.f, 0.f, 0.f, 0.f};
  const unsigned short* base = encB + (((size_t)ch * 2048 + b) << 10) + (t << 2);
#pragma unroll 8
  for (int i = 0; i < 64; ++i) {
    short4v e = *reinterpret_cast<const short4v*>(base + (size_t)i * 32768);
    float w = wl[i];
    acc.x = fmaf(w, bf2f((unsigned short)e[0]), acc.x);
    acc.y = fmaf(w, bf2f((unsigned short)e[1]), acc.y);
    acc.z = fmaf(w, bf2f((unsigned short)e[2]), acc.z);
    acc.w = fmaf(w, bf2f((unsigned short)e[3]), acc.w);
  }
  *reinterpret_cast<f32x4*>(((float*)pctx) + ((size_t)blockIdx.x << 10) + (t << 2)) = acc;
}

// ---------------- context partials fp32 (fallback path) --------------------------
__global__ __launch_bounds__(256) void k_ctx(const float* __restrict__ enc,
                                             const float* __restrict__ al,
                                             float* __restrict__ pctx) {
  const int b = blockIdx.x & 31, ch = blockIdx.x >> 5;
  const int t = threadIdx.x;
  __shared__ float wl[64];
  if (t < 64) wl[t] = al[(((ch << 6) + t) << 5) + b];
  __syncthreads();
  f32x4 acc = (f32x4){0.f, 0.f, 0.f, 0.f};
  const float* base = enc + (((size_t)ch * 2048 + b) << 10) + (t << 2);
#pragma unroll 8
  for (int i = 0; i < 64; ++i) {
    f32x4 e = *reinterpret_cast<const f32x4*>(base + (size_t)i * 32768);
    acc += wl[i] * e;
  }
  *reinterpret_cast<f32x4*>(((float*)pctx) + ((size_t)blockIdx.x << 10) + (t << 2)) = acc;
}

__global__ __launch_bounds__(256) void k_ctxred(const float* __restrict__ pctx,
                                                float* __restrict__ out) {
  int i = blockIdx.x * 256 + threadIdx.x;  // 32768 = b*1024 + e
  int b = i >> 10, e = i & 1023;
  float s = 0.f;
#pragma unroll
  for (int ch = 0; ch < 32; ++ch) s += pctx[(size_t)((ch << 5) + b) * 1024 + e];
  out[i] = s;
}

extern "C" void kernel_launch(void* const* d_in, const int* in_sizes, int n_in,
                              void* d_out, int out_size, void* d_ws, size_t ws_size,
                              hipStream_t stream) {
  const float* enc = (const float*)d_in[0];
  const float* mask = (const float*)d_in[1];
  const float* hidden = (const float*)d_in[2];
  const float* Wenc = (const float*)d_in[3];
  const float* battn = (const float*)d_in[4];
  const float* Whid = (const float*)d_in[5];
  const float* v = (const float*)d_in[6];
  float* out = (float*)d_out;          // [0,32768) context [B][ENC]; [32768,98304) alignment [L][B]
  char* ws = (char*)d_ws;

  const bool big = ws_size >= (size_t)140 * 1024 * 1024;
  char* base = big ? ws + ((size_t)128 << 20) : ws;
  unsigned short* encB = (unsigned short*)ws;                       // 128 MB (big only)
  unsigned short* WT = (unsigned short*)base;                       // 2 MB
  float* q = (float*)(base + (2u << 20));                           // 128 KB
  float* pq = (float*)(base + (2u << 20) + (128u << 10));           // 1 MB
  float* pl = (float*)(base + (3u << 20) + (128u << 10));           // 2 MB
  float* pctx = (float*)(base + (5u << 20) + (128u << 10));         // 4 MB
  float* align_out = out + 32768;

  k_wt<<<256, 256, 0, stream>>>(Wenc, WT);
  k_qpart<<<64, 128, 0, stream>>>(hidden, Whid, pq);
  k_qred<<<128, 256, 0, stream>>>(pq, battn, q);
  if (big) {
    k_enc_bf16<<<2048, 256, 0, stream>>>(enc, encB);
    k_logits_db<<<4096, 256, 0, stream>>>(encB, WT, q, v, pl);
    k_softmax<8><<<32, 256, 0, stream>>>(pl, mask, align_out);
    k_ctx_bf<<<1024, 256, 0, stream>>>(encB, align_out, pctx);
  } else {
    k_logits_cvt<<<4096, 256, 0, stream>>>(enc, WT, q, v, pl);
    k_softmax<8><<<32, 256, 0, stream>>>(pl, mask, align_out);
    k_ctx<<<1024, 256, 0, stream>>>(enc, align_out, pctx);
  }
  k_ctxred<<<128, 256, 0, stream>>>(pctx, out);
}

// Round 10
// 338.446 us; speedup vs baseline: 1.1389x; 1.1389x over previous
//
#include <hip/hip_runtime.h>
#include <stdint.h>

#define L_DIM 2048
#define B_DIM 32
#define ENC_DIM 1024
#define M_DIM (L_DIM * B_DIM)

typedef __attribute__((ext_vector_type(4))) float f32x4;
typedef __attribute__((ext_vector_type(4))) unsigned int uint4v;
typedef __attribute__((ext_vector_type(8))) short short8;
typedef __attribute__((ext_vector_type(4))) short short4v;
typedef __attribute__((ext_vector_type(4))) __bf16 bf16x4;

static __device__ __forceinline__ float fast_tanh(float x) {
  float cx = fminf(fmaxf(x, -15.f), 15.f);
  float e = __expf(2.f * cx);
  return (e - 1.f) * __frcp_rn(e + 1.f);
}

static __device__ __forceinline__ float bf2f(unsigned short u) {
  return __builtin_bit_cast(float, (unsigned int)u << 16);
}

static __device__ __forceinline__ void load_lds16(const void* g, void* l) {
  __builtin_amdgcn_global_load_lds((const __attribute__((address_space(1))) void*)g,
                                   (__attribute__((address_space(3))) void*)l, 16, 0, 0);
}

// ---------------- enc fp32 -> bf16 copy (64M elems) -------------------------------
__global__ __launch_bounds__(256) void k_enc_bf16(const float* __restrict__ enc,
                                                  unsigned short* __restrict__ encB) {
  const int t = blockIdx.x * 256 + threadIdx.x;   // 524288 threads
#pragma unroll
  for (int it = 0; it < 16; ++it) {
    size_t i = ((size_t)t + (size_t)it * 524288) << 3;   // 8 floats per thread-iter
    f32x4 a = *reinterpret_cast<const f32x4*>(enc + i);
    f32x4 b = *reinterpret_cast<const f32x4*>(enc + i + 4);
    bf16x4 pa = {(__bf16)a.x, (__bf16)a.y, (__bf16)a.z, (__bf16)a.w};
    bf16x4 pb = {(__bf16)b.x, (__bf16)b.y, (__bf16)b.z, (__bf16)b.w};
    union { bf16x4 v; unsigned int u[2]; } ua, ub;
    ua.v = pa; ub.v = pb;
    uint4v o;
    o.x = ua.u[0]; o.y = ua.u[1]; o.z = ub.u[0]; o.w = ub.u[1];
    *reinterpret_cast<uint4v*>(encB + i) = o;
  }
}

// ---------------- W_enc [K=1024][N=1024] fp32  ->  WT [N][K] bf16 -----------------
__global__ __launch_bounds__(256) void k_wt(const float* __restrict__ W,
                                            unsigned short* __restrict__ WT) {
  __shared__ float tile[64][65];
  const int t = threadIdx.x;
  const int k0 = (blockIdx.x & 15) << 6, n0 = (blockIdx.x >> 4) << 6;
#pragma unroll
  for (int i = 0; i < 16; ++i) {
    int idx = t + (i << 8);
    tile[idx >> 6][idx & 63] = W[(size_t)(k0 + (idx >> 6)) * 1024 + n0 + (idx & 63)];
  }
  __syncthreads();
#pragma unroll
  for (int i = 0; i < 16; ++i) {
    int idx = t + (i << 8);
    int r = idx >> 6, c = idx & 63;
    WT[(size_t)(n0 + r) * 1024 + k0 + c] =
        __builtin_bit_cast(unsigned short, (__bf16)tile[c][r]);
  }
}

// ---------------- q partial: grid 64 = 8 a-blocks x 8 h-blocks, 128 thr -----------
__global__ __launch_bounds__(128) void k_qpart(const float* __restrict__ hidden,
                                               const float* __restrict__ Wh,
                                               float* __restrict__ pq) {
  const int ablk = blockIdx.x & 7, hblk = blockIdx.x >> 3;
  const int a = (ablk << 7) + threadIdx.x;
  float acc[32];
#pragma unroll
  for (int b = 0; b < 32; ++b) acc[b] = 0.f;
  const int h0 = hblk << 7;
  for (int h = h0; h < h0 + 128; ++h) {
    float wv = Wh[(size_t)h * 1024 + a];
#pragma unroll
    for (int b = 0; b < 32; ++b) acc[b] = fmaf(hidden[(b << 10) + h], wv, acc[b]);
  }
#pragma unroll
  for (int b = 0; b < 32; ++b) pq[((size_t)hblk << 15) + (b << 10) + a] = acc[b];
}

__global__ __launch_bounds__(256) void k_qred(const float* __restrict__ pq,
                                              const float* __restrict__ ba,
                                              float* __restrict__ q) {
  int i = blockIdx.x * 256 + threadIdx.x;  // 32768
  float s = ba[i & 1023];
#pragma unroll
  for (int j = 0; j < 8; ++j) s += pq[((size_t)j << 15) + i];
  q[i] = s;
}

// ================= fused keys-GEMM + tanh.v reduction (R6 structure) =============
// 128x128 tile, BK=64, 4 waves, single-buffer 2-barrier loop (the proven 173us
// config). ONE change vs R6: epilogue reduction reuses As (dead after K-loop)
// instead of a separate red[] — LDS 33792->32768 so 4 blocks/CU fit (131072/32768
// = 4.0; at 33792 only 3 fit). Extra __syncthreads closes the WAR vs final-tile
// ds_reads. q folded into MFMA C-in. pl[nblk8][b][l] transposed output.
__global__ __launch_bounds__(256, 4) void k_logits_bf(const unsigned short* __restrict__ encB,
                                                      const unsigned short* __restrict__ WT,
                                                      const float* __restrict__ qv,
                                                      const float* __restrict__ v,
                                                      float* __restrict__ pl) {
  __shared__ __align__(16) unsigned short As[128 * 64];
  __shared__ __align__(16) unsigned short Bs[128 * 64];

  const int tid = threadIdx.x;
  const int xcd = blockIdx.x & 7, slot = blockIdx.x >> 3;
  const int nblk = slot & 7;
  const int mblk = xcd + ((slot >> 3) << 3);
  const int row0 = mblk << 7;
  const int n0 = nblk << 7;

  const int w = tid >> 6, lane = tid & 63;
  const int wr = w >> 1, wc = w & 1;
  const int g = lane >> 4, rr = lane & 15;

  float vreg[4];
#pragma unroll
  for (int nf = 0; nf < 4; ++nf) vreg[nf] = v[n0 + wc * 64 + nf * 16 + rr];

  f32x4 acc[4][4];
#pragma unroll
  for (int mf = 0; mf < 4; ++mf)
#pragma unroll
    for (int nf = 0; nf < 4; ++nf)
#pragma unroll
      for (int rg = 0; rg < 4; ++rg) {
        int b = ((mf & 1) << 4) + (g << 2) + rg;
        acc[mf][nf][rg] = qv[((size_t)b << 10) + n0 + wc * 64 + nf * 16 + rr];
      }

  const int srow = lane >> 3, sjj = lane & 7;   // staging row-offset / 16B-block

  for (int kt = 0; kt < 16; ++kt) {
    const int k0 = kt << 6;
    __syncthreads();
#pragma unroll
    for (int c = 0; c < 4; ++c) {
      int r = w * 32 + c * 8 + srow;
      int blk = sjj ^ (r & 7);
      const char* bsrc = (const char*)WT + (((size_t)(n0 + r) << 10) + k0) * 2 + (blk << 4);
      load_lds16(bsrc, (void*)&Bs[(w * 32 + c * 8) * 64]);
      const char* asrc = (const char*)encB + (((size_t)(row0 + r) << 10) + k0) * 2 + (blk << 4);
      load_lds16(asrc, (void*)&As[(w * 32 + c * 8) * 64]);
    }
    __syncthreads();
#pragma unroll
    for (int kk = 0; kk < 2; ++kk) {
      short8 af[4], bfr[4];
#pragma unroll
      for (int mf = 0; mf < 4; ++mf) {
        int r = wr * 64 + mf * 16 + rr;
        int blk = (kk * 4 + g) ^ (r & 7);
        af[mf] = *reinterpret_cast<const short8*>(&As[r * 64 + (blk << 3)]);
      }
#pragma unroll
      for (int nf = 0; nf < 4; ++nf) {
        int r = wc * 64 + nf * 16 + rr;
        int blk = (kk * 4 + g) ^ (r & 7);
        bfr[nf] = *reinterpret_cast<const short8*>(&Bs[r * 64 + (blk << 3)]);
      }
#pragma unroll
      for (int mf = 0; mf < 4; ++mf)
#pragma unroll
        for (int nf = 0; nf < 4; ++nf)
          acc[mf][nf] = __builtin_amdgcn_mfma_f32_16x16x32_bf16(af[mf], bfr[nf], acc[mf][nf], 0, 0, 0);
    }
  }

  // WAR fence: other waves may still be ds_reading As for their last MFMAs
  __syncthreads();
  float* red = reinterpret_cast<float*>(&As[0]);   // [2][128] floats, reuse LDS

#pragma unroll
  for (int mf = 0; mf < 4; ++mf) {
#pragma unroll
    for (int rg = 0; rg < 4; ++rg) {
      int lrow = wr * 64 + mf * 16 + g * 4 + rg;
      float s = 0.f;
#pragma unroll
      for (int nf = 0; nf < 4; ++nf) s += fast_tanh(acc[mf][nf][rg]) * vreg[nf];
      s += __shfl_xor(s, 1);
      s += __shfl_xor(s, 2);
      s += __shfl_xor(s, 4);
      s += __shfl_xor(s, 8);
      if (rr == 0) red[wc * 128 + lrow] = s;
    }
  }
  __syncthreads();
  if (tid < 128) {
    int row = row0 + tid;
    pl[((size_t)nblk << 16) + ((size_t)(row & 31) << 11) + (row >> 5)] =
        red[tid] + red[128 + tid];
  }
}

// ---- fallback (small ws): R3 kernel — A fp32->cvt->ds_write, 128^2, pl[8] -------
__global__ __launch_bounds__(256, 3) void k_logits_cvt(const float* __restrict__ enc,
                                                       const unsigned short* __restrict__ WT,
                                                       const float* __restrict__ qv,
                                                       const float* __restrict__ v,
                                                       float* __restrict__ pl) {
  __shared__ __align__(16) unsigned short As[128 * 64];
  __shared__ __align__(16) unsigned short Bs[128 * 64];
  __shared__ float red[2][128];

  const int tid = threadIdx.x;
  const int xcd = blockIdx.x & 7, slot = blockIdx.x >> 3;
  const int nblk = slot & 7;
  const int mblk = xcd + ((slot >> 3) << 3);
  const int row0 = mblk << 7;
  const int n0 = nblk << 7;

  const int w = tid >> 6, lane = tid & 63;
  const int wr = w >> 1, wc = w & 1;
  const int g = lane >> 4, rr = lane & 15;

  float vreg[4];
#pragma unroll
  for (int nf = 0; nf < 4; ++nf) vreg[nf] = v[n0 + wc * 64 + nf * 16 + rr];

  f32x4 acc[4][4];
#pragma unroll
  for (int mf = 0; mf < 4; ++mf)
#pragma unroll
    for (int nf = 0; nf < 4; ++nf)
#pragma unroll
      for (int rg = 0; rg < 4; ++rg) {
        int b = ((mf & 1) << 4) + (g << 2) + rg;
        acc[mf][nf][rg] = qv[((size_t)b << 10) + n0 + wc * 64 + nf * 16 + rr];
      }

  const int ar = tid >> 4;
  const int ac4 = tid & 15;
  const int ablk = ((ac4 >> 1) ^ (ar & 7));
  const int brow = lane >> 3, bjj = lane & 7;

  for (int kt = 0; kt < 16; ++kt) {
    const int k0 = kt << 6;
    __syncthreads();
#pragma unroll
    for (int c = 0; c < 4; ++c) {
      int nrow = w * 32 + c * 8 + brow;
      int blk = bjj ^ (brow & 7);
      const char* src = (const char*)WT + (((size_t)(n0 + nrow) << 10) + k0) * 2 + (blk << 4);
      load_lds16(src, (void*)&Bs[(w * 32 + c * 8) * 64]);
    }
#pragma unroll
    for (int i = 0; i < 8; ++i) {
      int r = ar + (i << 4);
      f32x4 a4 = *reinterpret_cast<const f32x4*>(enc + (((size_t)(row0 + r)) << 10) + k0 + (ac4 << 2));
      bf16x4 pk = {(__bf16)a4.x, (__bf16)a4.y, (__bf16)a4.z, (__bf16)a4.w};
      *reinterpret_cast<bf16x4*>(&As[r * 64 + (ablk << 3) + ((ac4 & 1) << 2)]) = pk;
    }
    __syncthreads();
#pragma unroll
    for (int kk = 0; kk < 2; ++kk) {
      short8 af[4], bfr[4];
#pragma unroll
      for (int mf = 0; mf < 4; ++mf) {
        int r = wr * 64 + mf * 16 + rr;
        int blk = (kk * 4 + g) ^ (r & 7);
        af[mf] = *reinterpret_cast<const short8*>(&As[r * 64 + (blk << 3)]);
      }
#pragma unroll
      for (int nf = 0; nf < 4; ++nf) {
        int r = wc * 64 + nf * 16 + rr;
        int blk = (kk * 4 + g) ^ (r & 7);
        bfr[nf] = *reinterpret_cast<const short8*>(&Bs[r * 64 + (blk << 3)]);
      }
#pragma unroll
      for (int mf = 0; mf < 4; ++mf)
#pragma unroll
        for (int nf = 0; nf < 4; ++nf)
          acc[mf][nf] = __builtin_amdgcn_mfma_f32_16x16x32_bf16(af[mf], bfr[nf], acc[mf][nf], 0, 0, 0);
    }
  }

#pragma unroll
  for (int mf = 0; mf < 4; ++mf) {
#pragma unroll
    for (int rg = 0; rg < 4; ++rg) {
      int lrow = wr * 64 + mf * 16 + g * 4 + rg;
      float s = 0.f;
#pragma unroll
      for (int nf = 0; nf < 4; ++nf) s += fast_tanh(acc[mf][nf][rg]) * vreg[nf];
      s += __shfl_xor(s, 1);
      s += __shfl_xor(s, 2);
      s += __shfl_xor(s, 4);
      s += __shfl_xor(s, 8);
      if (rr == 0) red[wc][lrow] = s;
    }
  }
  __syncthreads();
  if (tid < 128) {
    int row = row0 + tid;
    pl[((size_t)nblk << 16) + ((size_t)(row & 31) << 11) + (row >> 5)] =
        red[0][tid] + red[1][tid];
  }
}

// ---------------- softmax over l, per b (NP partial planes) ----------------------
template <int NP>
__global__ __launch_bounds__(256) void k_softmax(const float* __restrict__ pl,
                                                 const float* __restrict__ mask,
                                                 float* __restrict__ al) {
  const int b = blockIdx.x, t = threadIdx.x;
  __shared__ float sr[256];
  float lg[8];
  float mx = -3.4e38f;
#pragma unroll
  for (int i = 0; i < 8; ++i) {
    int l = t + (i << 8);
    float s = mask[(l << 5) + b];
#pragma unroll
    for (int nb = 0; nb < NP; ++nb) s += pl[((size_t)nb << 16) + (b << 11) + l];
    lg[i] = s;
    mx = fmaxf(mx, s);
  }
  sr[t] = mx;
  __syncthreads();
  for (int off = 128; off > 0; off >>= 1) {
    if (t < off) sr[t] = fmaxf(sr[t], sr[t + off]);
    __syncthreads();
  }
  const float M = sr[0];
  __syncthreads();
  float sum = 0.f;
#pragma unroll
  for (int i = 0; i < 8; ++i) {
    lg[i] = __expf(lg[i] - M);
    sum += lg[i];
  }
  sr[t] = sum;
  __syncthreads();
  for (int off = 128; off > 0; off >>= 1) {
    if (t < off) sr[t] += sr[t + off];
    __syncthreads();
  }
  const float inv = 1.f / sr[0];
#pragma unroll
  for (int i = 0; i < 8; ++i) {
    int l = t + (i << 8);
    al[(l << 5) + b] = lg[i] * inv;
  }
}

// ---------------- context partials from bf16 enc: grid = 32 chunks x 32 b --------
__global__ __launch_bounds__(256) void k_ctx_bf(const unsigned short* __restrict__ encB,
                                                const float* __restrict__ al,
                                                float* __restrict__ pctx) {
  const int b = blockIdx.x & 31, ch = blockIdx.x >> 5;
  const int t = threadIdx.x;
  __shared__ float wl[64];
  if (t < 64) wl[t] = al[(((ch << 6) + t) << 5) + b];
  __syncthreads();
  f32x4 acc = (f32x4){0.f, 0.f, 0.f, 0.f};
  const unsigned short* base = encB + (((size_t)ch * 2048 + b) << 10) + (t << 2);
#pragma unroll 8
  for (int i = 0; i < 64; ++i) {
    short4v e = *reinterpret_cast<const short4v*>(base + (size_t)i * 32768);
    float w = wl[i];
    acc.x = fmaf(w, bf2f((unsigned short)e[0]), acc.x);
    acc.y = fmaf(w, bf2f((unsigned short)e[1]), acc.y);
    acc.z = fmaf(w, bf2f((unsigned short)e[2]), acc.z);
    acc.w = fmaf(w, bf2f((unsigned short)e[3]), acc.w);
  }
  *reinterpret_cast<f32x4*>(((float*)pctx) + ((size_t)blockIdx.x << 10) + (t << 2)) = acc;
}

// ---------------- context partials fp32 (fallback path) --------------------------
__global__ __launch_bounds__(256) void k_ctx(const float* __restrict__ enc,
                                             const float* __restrict__ al,
                                             float* __restrict__ pctx) {
  const int b = blockIdx.x & 31, ch = blockIdx.x >> 5;
  const int t = threadIdx.x;
  __shared__ float wl[64];
  if (t < 64) wl[t] = al[(((ch << 6) + t) << 5) + b];
  __syncthreads();
  f32x4 acc = (f32x4){0.f, 0.f, 0.f, 0.f};
  const float* base = enc + (((size_t)ch * 2048 + b) << 10) + (t << 2);
#pragma unroll 8
  for (int i = 0; i < 64; ++i) {
    f32x4 e = *reinterpret_cast<const f32x4*>(base + (size_t)i * 32768);
    acc += wl[i] * e;
  }
  *reinterpret_cast<f32x4*>(((float*)pctx) + ((size_t)blockIdx.x << 10) + (t << 2)) = acc;
}

__global__ __launch_bounds__(256) void k_ctxred(const float* __restrict__ pctx,
                                                float* __restrict__ out) {
  int i = blockIdx.x * 256 + threadIdx.x;  // 32768 = b*1024 + e
  int b = i >> 10, e = i & 1023;
  float s = 0.f;
#pragma unroll
  for (int ch = 0; ch < 32; ++ch) s += pctx[(size_t)((ch << 5) + b) * 1024 + e];
  out[i] = s;
}

extern "C" void kernel_launch(void* const* d_in, const int* in_sizes, int n_in,
                              void* d_out, int out_size, void* d_ws, size_t ws_size,
                              hipStream_t stream) {
  const float* enc = (const float*)d_in[0];
  const float* mask = (const float*)d_in[1];
  const float* hidden = (const float*)d_in[2];
  const float* Wenc = (const float*)d_in[3];
  const float* battn = (const float*)d_in[4];
  const float* Whid = (const float*)d_in[5];
  const float* v = (const float*)d_in[6];
  float* out = (float*)d_out;          // [0,32768) context [B][ENC]; [32768,98304) alignment [L][B]
  char* ws = (char*)d_ws;

  const bool big = ws_size >= (size_t)140 * 1024 * 1024;
  char* base = big ? ws + ((size_t)128 << 20) : ws;
  unsigned short* encB = (unsigned short*)ws;                       // 128 MB (big only)
  unsigned short* WT = (unsigned short*)base;                       // 2 MB
  float* q = (float*)(base + (2u << 20));                           // 128 KB
  float* pq = (float*)(base + (2u << 20) + (128u << 10));           // 1 MB
  float* pl = (float*)(base + (3u << 20) + (128u << 10));           // 2 MB
  float* pctx = (float*)(base + (5u << 20) + (128u << 10));         // 4 MB
  float* align_out = out + 32768;

  k_wt<<<256, 256, 0, stream>>>(Wenc, WT);
  k_qpart<<<64, 128, 0, stream>>>(hidden, Whid, pq);
  k_qred<<<128, 256, 0, stream>>>(pq, battn, q);
  if (big) {
    k_enc_bf16<<<2048, 256, 0, stream>>>(enc, encB);
    k_logits_bf<<<4096, 256, 0, stream>>>(encB, WT, q, v, pl);
    k_softmax<8><<<32, 256, 0, stream>>>(pl, mask, align_out);
    k_ctx_bf<<<1024, 256, 0, stream>>>(encB, align_out, pctx);
  } else {
    k_logits_cvt<<<4096, 256, 0, stream>>>(enc, WT, q, v, pl);
    k_softmax<8><<<32, 256, 0, stream>>>(pl, mask, align_out);
    k_ctx<<<1024, 256, 0, stream>>>(enc, align_out, pctx);
  }
  k_ctxred<<<128, 256, 0, stream>>>(pctx, out);
}

// Round 11
// 336.652 us; speedup vs baseline: 1.1449x; 1.0053x over previous
//
#include <hip/hip_runtime.h>
#include <stdint.h>

#define L_DIM 2048
#define B_DIM 32
#define ENC_DIM 1024
#define M_DIM (L_DIM * B_DIM)

typedef __attribute__((ext_vector_type(4))) float f32x4;
typedef __attribute__((ext_vector_type(4))) unsigned int uint4v;
typedef __attribute__((ext_vector_type(8))) short short8;
typedef __attribute__((ext_vector_type(4))) short short4v;
typedef __attribute__((ext_vector_type(4))) __bf16 bf16x4;

static __device__ __forceinline__ float fast_tanh(float x) {
  float cx = fminf(fmaxf(x, -15.f), 15.f);
  float e = __expf(2.f * cx);
  return (e - 1.f) * __frcp_rn(e + 1.f);
}

static __device__ __forceinline__ float bf2f(unsigned short u) {
  return __builtin_bit_cast(float, (unsigned int)u << 16);
}

static __device__ __forceinline__ void load_lds16(const void* g, void* l) {
  __builtin_amdgcn_global_load_lds((const __attribute__((address_space(1))) void*)g,
                                   (__attribute__((address_space(3))) void*)l, 16, 0, 0);
}

// ---------------- enc fp32 -> bf16 copy (64M elems) -------------------------------
__global__ __launch_bounds__(256) void k_enc_bf16(const float* __restrict__ enc,
                                                  unsigned short* __restrict__ encB) {
  const int t = blockIdx.x * 256 + threadIdx.x;   // 524288 threads
#pragma unroll
  for (int it = 0; it < 16; ++it) {
    size_t i = ((size_t)t + (size_t)it * 524288) << 3;   // 8 floats per thread-iter
    f32x4 a = *reinterpret_cast<const f32x4*>(enc + i);
    f32x4 b = *reinterpret_cast<const f32x4*>(enc + i + 4);
    bf16x4 pa = {(__bf16)a.x, (__bf16)a.y, (__bf16)a.z, (__bf16)a.w};
    bf16x4 pb = {(__bf16)b.x, (__bf16)b.y, (__bf16)b.z, (__bf16)b.w};
    union { bf16x4 v; unsigned int u[2]; } ua, ub;
    ua.v = pa; ub.v = pb;
    uint4v o;
    o.x = ua.u[0]; o.y = ua.u[1]; o.z = ub.u[0]; o.w = ub.u[1];
    *reinterpret_cast<uint4v*>(encB + i) = o;
  }
}

// ---------------- W_enc [K=1024][N=1024] fp32  ->  WT [N][K] bf16 -----------------
__global__ __launch_bounds__(256) void k_wt(const float* __restrict__ W,
                                            unsigned short* __restrict__ WT) {
  __shared__ float tile[64][65];
  const int t = threadIdx.x;
  const int k0 = (blockIdx.x & 15) << 6, n0 = (blockIdx.x >> 4) << 6;
#pragma unroll
  for (int i = 0; i < 16; ++i) {
    int idx = t + (i << 8);
    tile[idx >> 6][idx & 63] = W[(size_t)(k0 + (idx >> 6)) * 1024 + n0 + (idx & 63)];
  }
  __syncthreads();
#pragma unroll
  for (int i = 0; i < 16; ++i) {
    int idx = t + (i << 8);
    int r = idx >> 6, c = idx & 63;
    WT[(size_t)(n0 + r) * 1024 + k0 + c] =
        __builtin_bit_cast(unsigned short, (__bf16)tile[c][r]);
  }
}

// ---------------- q partial: grid 64 = 8 a-blocks x 8 h-blocks, 128 thr -----------
__global__ __launch_bounds__(128) void k_qpart(const float* __restrict__ hidden,
                                               const float* __restrict__ Wh,
                                               float* __restrict__ pq) {
  const int ablk = blockIdx.x & 7, hblk = blockIdx.x >> 3;
  const int a = (ablk << 7) + threadIdx.x;
  float acc[32];
#pragma unroll
  for (int b = 0; b < 32; ++b) acc[b] = 0.f;
  const int h0 = hblk << 7;
  for (int h = h0; h < h0 + 128; ++h) {
    float wv = Wh[(size_t)h * 1024 + a];
#pragma unroll
    for (int b = 0; b < 32; ++b) acc[b] = fmaf(hidden[(b << 10) + h], wv, acc[b]);
  }
#pragma unroll
  for (int b = 0; b < 32; ++b) pq[((size_t)hblk << 15) + (b << 10) + a] = acc[b];
}

__global__ __launch_bounds__(256) void k_qred(const float* __restrict__ pq,
                                              const float* __restrict__ ba,
                                              float* __restrict__ q) {
  int i = blockIdx.x * 256 + threadIdx.x;  // 32768
  float s = ba[i & 1023];
#pragma unroll
  for (int j = 0; j < 8; ++j) s += pq[((size_t)j << 15) + i];
  q[i] = s;
}

// ================= fused keys-GEMM + tanh.v reduction (R6 structure) =============
// 128x128 tile, BK=64, 4 waves, single-buffer 2-barrier loop. Change vs R10:
// ALL loop-invariant addressing hoisted out of the K-loop —
//   * 8 staging voffsets precomputed as 32-bit unsigned (saddr+voffset form),
//     advanced by a single koff += 128 per tile (1 v_add per load in-loop)
//   * 16 ds_read byte-offsets precomputed (tile-invariant, ~0 in-loop VALU)
//   * 8 LDS dst pointers precomputed
// R10 PMC showed ~320 VALU instrs/tile (VALUBusy 40%) from in-loop address
// recomputation; intrinsic need is ~60. launch_bounds (256,3): extra live
// pointer state (+~30 VGPR) must not spill (R2 lesson); 3 blocks/CU is the
// observed cap anyway. q folded into MFMA C-in. pl[nblk8][b][l] output.
__global__ __launch_bounds__(256, 3) void k_logits_bf(const unsigned short* __restrict__ encB,
                                                      const unsigned short* __restrict__ WT,
                                                      const float* __restrict__ qv,
                                                      const float* __restrict__ v,
                                                      float* __restrict__ pl) {
  __shared__ __align__(16) unsigned short As[128 * 64];
  __shared__ __align__(16) unsigned short Bs[128 * 64];

  const int tid = threadIdx.x;
  const int xcd = blockIdx.x & 7, slot = blockIdx.x >> 3;
  const int nblk = slot & 7;
  const int mblk = xcd + ((slot >> 3) << 3);
  const int row0 = mblk << 7;
  const int n0 = nblk << 7;

  const int w = tid >> 6, lane = tid & 63;
  const int wr = w >> 1, wc = w & 1;
  const int g = lane >> 4, rr = lane & 15;
  const int srow = lane >> 3, sjj = lane & 7;

  float vreg[4];
#pragma unroll
  for (int nf = 0; nf < 4; ++nf) vreg[nf] = v[n0 + wc * 64 + nf * 16 + rr];

  f32x4 acc[4][4];
#pragma unroll
  for (int mf = 0; mf < 4; ++mf)
#pragma unroll
    for (int nf = 0; nf < 4; ++nf)
#pragma unroll
      for (int rg = 0; rg < 4; ++rg) {
        int b = ((mf & 1) << 4) + (g << 2) + rg;
        acc[mf][nf][rg] = qv[((size_t)b << 10) + n0 + wc * 64 + nf * 16 + rr];
      }

  // ---- hoisted staging state: 32-bit voffsets + LDS dst pointers ----
  unsigned aoffg[4], boffg[4];
  unsigned short *adst[4], *bdst[4];
#pragma unroll
  for (int c = 0; c < 4; ++c) {
    int r = w * 32 + c * 8 + srow;
    int blk = sjj ^ (r & 7);
    boffg[c] = ((unsigned)((n0 + r) << 10) << 1) + (blk << 4);
    aoffg[c] = ((unsigned)((row0 + r) << 10) << 1) + (blk << 4);
    bdst[c] = &Bs[(w * 32 + c * 8) * 64];
    adst[c] = &As[(w * 32 + c * 8) * 64];
  }
  // ---- hoisted ds_read byte-offsets (tile-invariant) ----
  int aoffl[2][4], boffl[2][4];
#pragma unroll
  for (int kk = 0; kk < 2; ++kk)
#pragma unroll
    for (int f = 0; f < 4; ++f) {
      int ra = wr * 64 + f * 16 + rr;
      aoffl[kk][f] = (ra * 64 + (((kk * 4 + g) ^ (ra & 7)) << 3)) * 2;
      int rb = wc * 64 + f * 16 + rr;
      boffl[kk][f] = (rb * 64 + (((kk * 4 + g) ^ (rb & 7)) << 3)) * 2;
    }
  const char* asbase = reinterpret_cast<const char*>(&As[0]);
  const char* bsbase = reinterpret_cast<const char*>(&Bs[0]);

  unsigned koff = 0;   // +128 bytes per K-tile
  for (int kt = 0; kt < 16; ++kt) {
    __syncthreads();
#pragma unroll
    for (int c = 0; c < 4; ++c) {
      load_lds16((const char*)WT + (size_t)(boffg[c] + koff), bdst[c]);
      load_lds16((const char*)encB + (size_t)(aoffg[c] + koff), adst[c]);
    }
    koff += 128;
    __syncthreads();
#pragma unroll
    for (int kk = 0; kk < 2; ++kk) {
      short8 af[4], bfr[4];
#pragma unroll
      for (int mf = 0; mf < 4; ++mf)
        af[mf] = *reinterpret_cast<const short8*>(asbase + aoffl[kk][mf]);
#pragma unroll
      for (int nf = 0; nf < 4; ++nf)
        bfr[nf] = *reinterpret_cast<const short8*>(bsbase + boffl[kk][nf]);
#pragma unroll
      for (int mf = 0; mf < 4; ++mf)
#pragma unroll
        for (int nf = 0; nf < 4; ++nf)
          acc[mf][nf] = __builtin_amdgcn_mfma_f32_16x16x32_bf16(af[mf], bfr[nf], acc[mf][nf], 0, 0, 0);
    }
  }

  // WAR fence: other waves may still be ds_reading As for their last MFMAs
  __syncthreads();
  float* red = reinterpret_cast<float*>(&As[0]);   // [2][128] floats, reuse LDS

#pragma unroll
  for (int mf = 0; mf < 4; ++mf) {
#pragma unroll
    for (int rg = 0; rg < 4; ++rg) {
      int lrow = wr * 64 + mf * 16 + g * 4 + rg;
      float s = 0.f;
#pragma unroll
      for (int nf = 0; nf < 4; ++nf) s += fast_tanh(acc[mf][nf][rg]) * vreg[nf];
      s += __shfl_xor(s, 1);
      s += __shfl_xor(s, 2);
      s += __shfl_xor(s, 4);
      s += __shfl_xor(s, 8);
      if (rr == 0) red[wc * 128 + lrow] = s;
    }
  }
  __syncthreads();
  if (tid < 128) {
    int row = row0 + tid;
    pl[((size_t)nblk << 16) + ((size_t)(row & 31) << 11) + (row >> 5)] =
        red[tid] + red[128 + tid];
  }
}

// ---- fallback (small ws): R3 kernel — A fp32->cvt->ds_write, 128^2, pl[8] -------
__global__ __launch_bounds__(256, 3) void k_logits_cvt(const float* __restrict__ enc,
                                                       const unsigned short* __restrict__ WT,
                                                       const float* __restrict__ qv,
                                                       const float* __restrict__ v,
                                                       float* __restrict__ pl) {
  __shared__ __align__(16) unsigned short As[128 * 64];
  __shared__ __align__(16) unsigned short Bs[128 * 64];
  __shared__ float red[2][128];

  const int tid = threadIdx.x;
  const int xcd = blockIdx.x & 7, slot = blockIdx.x >> 3;
  const int nblk = slot & 7;
  const int mblk = xcd + ((slot >> 3) << 3);
  const int row0 = mblk << 7;
  const int n0 = nblk << 7;

  const int w = tid >> 6, lane = tid & 63;
  const int wr = w >> 1, wc = w & 1;
  const int g = lane >> 4, rr = lane & 15;

  float vreg[4];
#pragma unroll
  for (int nf = 0; nf < 4; ++nf) vreg[nf] = v[n0 + wc * 64 + nf * 16 + rr];

  f32x4 acc[4][4];
#pragma unroll
  for (int mf = 0; mf < 4; ++mf)
#pragma unroll
    for (int nf = 0; nf < 4; ++nf)
#pragma unroll
      for (int rg = 0; rg < 4; ++rg) {
        int b = ((mf & 1) << 4) + (g << 2) + rg;
        acc[mf][nf][rg] = qv[((size_t)b << 10) + n0 + wc * 64 + nf * 16 + rr];
      }

  const int ar = tid >> 4;
  const int ac4 = tid & 15;
  const int ablk = ((ac4 >> 1) ^ (ar & 7));
  const int brow = lane >> 3, bjj = lane & 7;

  for (int kt = 0; kt < 16; ++kt) {
    const int k0 = kt << 6;
    __syncthreads();
#pragma unroll
    for (int c = 0; c < 4; ++c) {
      int nrow = w * 32 + c * 8 + brow;
      int blk = bjj ^ (brow & 7);
      const char* src = (const char*)WT + (((size_t)(n0 + nrow) << 10) + k0) * 2 + (blk << 4);
      load_lds16(src, (void*)&Bs[(w * 32 + c * 8) * 64]);
    }
#pragma unroll
    for (int i = 0; i < 8; ++i) {
      int r = ar + (i << 4);
      f32x4 a4 = *reinterpret_cast<const f32x4*>(enc + (((size_t)(row0 + r)) << 10) + k0 + (ac4 << 2));
      bf16x4 pk = {(__bf16)a4.x, (__bf16)a4.y, (__bf16)a4.z, (__bf16)a4.w};
      *reinterpret_cast<bf16x4*>(&As[r * 64 + (ablk << 3) + ((ac4 & 1) << 2)]) = pk;
    }
    __syncthreads();
#pragma unroll
    for (int kk = 0; kk < 2; ++kk) {
      short8 af[4], bfr[4];
#pragma unroll
      for (int mf = 0; mf < 4; ++mf) {
        int r = wr * 64 + mf * 16 + rr;
        int blk = (kk * 4 + g) ^ (r & 7);
        af[mf] = *reinterpret_cast<const short8*>(&As[r * 64 + (blk << 3)]);
      }
#pragma unroll
      for (int nf = 0; nf < 4; ++nf) {
        int r = wc * 64 + nf * 16 + rr;
        int blk = (kk * 4 + g) ^ (r & 7);
        bfr[nf] = *reinterpret_cast<const short8*>(&Bs[r * 64 + (blk << 3)]);
      }
#pragma unroll
      for (int mf = 0; mf < 4; ++mf)
#pragma unroll
        for (int nf = 0; nf < 4; ++nf)
          acc[mf][nf] = __builtin_amdgcn_mfma_f32_16x16x32_bf16(af[mf], bfr[nf], acc[mf][nf], 0, 0, 0);
    }
  }

#pragma unroll
  for (int mf = 0; mf < 4; ++mf) {
#pragma unroll
    for (int rg = 0; rg < 4; ++rg) {
      int lrow = wr * 64 + mf * 16 + g * 4 + rg;
      float s = 0.f;
#pragma unroll
      for (int nf = 0; nf < 4; ++nf) s += fast_tanh(acc[mf][nf][rg]) * vreg[nf];
      s += __shfl_xor(s, 1);
      s += __shfl_xor(s, 2);
      s += __shfl_xor(s, 4);
      s += __shfl_xor(s, 8);
      if (rr == 0) red[wc][lrow] = s;
    }
  }
  __syncthreads();
  if (tid < 128) {
    int row = row0 + tid;
    pl[((size_t)nblk << 16) + ((size_t)(row & 31) << 11) + (row >> 5)] =
        red[0][tid] + red[1][tid];
  }
}

// ---------------- softmax over l, per b (NP partial planes) ----------------------
template <int NP>
__global__ __launch_bounds__(256) void k_softmax(const float* __restrict__ pl,
                                                 const float* __restrict__ mask,
                                                 float* __restrict__ al) {
  const int b = blockIdx.x, t = threadIdx.x;
  __shared__ float sr[256];
  float lg[8];
  float mx = -3.4e38f;
#pragma unroll
  for (int i = 0; i < 8; ++i) {
    int l = t + (i << 8);
    float s = mask[(l << 5) + b];
#pragma unroll
    for (int nb = 0; nb < NP; ++nb) s += pl[((size_t)nb << 16) + (b << 11) + l];
    lg[i] = s;
    mx = fmaxf(mx, s);
  }
  sr[t] = mx;
  __syncthreads();
  for (int off = 128; off > 0; off >>= 1) {
    if (t < off) sr[t] = fmaxf(sr[t], sr[t + off]);
    __syncthreads();
  }
  const float M = sr[0];
  __syncthreads();
  float sum = 0.f;
#pragma unroll
  for (int i = 0; i < 8; ++i) {
    lg[i] = __expf(lg[i] - M);
    sum += lg[i];
  }
  sr[t] = sum;
  __syncthreads();
  for (int off = 128; off > 0; off >>= 1) {
    if (t < off) sr[t] += sr[t + off];
    __syncthreads();
  }
  const float inv = 1.f / sr[0];
#pragma unroll
  for (int i = 0; i < 8; ++i) {
    int l = t + (i << 8);
    al[(l << 5) + b] = lg[i] * inv;
  }
}

// ---------------- context partials from bf16 enc: grid = 32 chunks x 32 b --------
__global__ __launch_bounds__(256) void k_ctx_bf(const unsigned short* __restrict__ encB,
                                                const float* __restrict__ al,
                                                float* __restrict__ pctx) {
  const int b = blockIdx.x & 31, ch = blockIdx.x >> 5;
  const int t = threadIdx.x;
  __shared__ float wl[64];
  if (t < 64) wl[t] = al[(((ch << 6) + t) << 5) + b];
  __syncthreads();
  f32x4 acc = (f32x4){0.f, 0.f, 0.f, 0.f};
  const unsigned short* base = encB + (((size_t)ch * 2048 + b) << 10) + (t << 2);
#pragma unroll 8
  for (int i = 0; i < 64; ++i) {
    short4v e = *reinterpret_cast<const short4v*>(base + (size_t)i * 32768);
    float w = wl[i];
    acc.x = fmaf(w, bf2f((unsigned short)e[0]), acc.x);
    acc.y = fmaf(w, bf2f((unsigned short)e[1]), acc.y);
    acc.z = fmaf(w, bf2f((unsigned short)e[2]), acc.z);
    acc.w = fmaf(w, bf2f((unsigned short)e[3]), acc.w);
  }
  *reinterpret_cast<f32x4*>(((float*)pctx) + ((size_t)blockIdx.x << 10) + (t << 2)) = acc;
}

// ---------------- context partials fp32 (fallback path) --------------------------
__global__ __launch_bounds__(256) void k_ctx(const float* __restrict__ enc,
                                             const float* __restrict__ al,
                                             float* __restrict__ pctx) {
  const int b = blockIdx.x & 31, ch = blockIdx.x >> 5;
  const int t = threadIdx.x;
  __shared__ float wl[64];
  if (t < 64) wl[t] = al[(((ch << 6) + t) << 5) + b];
  __syncthreads();
  f32x4 acc = (f32x4){0.f, 0.f, 0.f, 0.f};
  const float* base = enc + (((size_t)ch * 2048 + b) << 10) + (t << 2);
#pragma unroll 8
  for (int i = 0; i < 64; ++i) {
    f32x4 e = *reinterpret_cast<const f32x4*>(base + (size_t)i * 32768);
    acc += wl[i] * e;
  }
  *reinterpret_cast<f32x4*>(((float*)pctx) + ((size_t)blockIdx.x << 10) + (t << 2)) = acc;
}

__global__ __launch_bounds__(256) void k_ctxred(const float* __restrict__ pctx,
                                                float* __restrict__ out) {
  int i = blockIdx.x * 256 + threadIdx.x;  // 32768 = b*1024 + e
  int b = i >> 10, e = i & 1023;
  float s = 0.f;
#pragma unroll
  for (int ch = 0; ch < 32; ++ch) s += pctx[(size_t)((ch << 5) + b) * 1024 + e];
  out[i] = s;
}

extern "C" void kernel_launch(void* const* d_in, const int* in_sizes, int n_in,
                              void* d_out, int out_size, void* d_ws, size_t ws_size,
                              hipStream_t stream) {
  const float* enc = (const float*)d_in[0];
  const float* mask = (const float*)d_in[1];
  const float* hidden = (const float*)d_in[2];
  const float* Wenc = (const float*)d_in[3];
  const float* battn = (const float*)d_in[4];
  const float* Whid = (const float*)d_in[5];
  const float* v = (const float*)d_in[6];
  float* out = (float*)d_out;          // [0,32768) context [B][ENC]; [32768,98304) alignment [L][B]
  char* ws = (char*)d_ws;

  const bool big = ws_size >= (size_t)140 * 1024 * 1024;
  char* base = big ? ws + ((size_t)128 << 20) : ws;
  unsigned short* encB = (unsigned short*)ws;                       // 128 MB (big only)
  unsigned short* WT = (unsigned short*)base;                       // 2 MB
  float* q = (float*)(base + (2u << 20));                           // 128 KB
  float* pq = (float*)(base + (2u << 20) + (128u << 10));           // 1 MB
  float* pl = (float*)(base + (3u << 20) + (128u << 10));           // 2 MB
  float* pctx = (float*)(base + (5u << 20) + (128u << 10));         // 4 MB
  float* align_out = out + 32768;

  k_wt<<<256, 256, 0, stream>>>(Wenc, WT);
  k_qpart<<<64, 128, 0, stream>>>(hidden, Whid, pq);
  k_qred<<<128, 256, 0, stream>>>(pq, battn, q);
  if (big) {
    k_enc_bf16<<<2048, 256, 0, stream>>>(enc, encB);
    k_logits_bf<<<4096, 256, 0, stream>>>(encB, WT, q, v, pl);
    k_softmax<8><<<32, 256, 0, stream>>>(pl, mask, align_out);
    k_ctx_bf<<<1024, 256, 0, stream>>>(encB, align_out, pctx);
  } else {
    k_logits_cvt<<<4096, 256, 0, stream>>>(enc, WT, q, v, pl);
    k_softmax<8><<<32, 256, 0, stream>>>(pl, mask, align_out);
    k_ctx<<<1024, 256, 0, stream>>>(enc, align_out, pctx);
  }
  k_ctxred<<<128, 256, 0, stream>>>(pctx, out);
}